// Round 1
// baseline (887.831 us; speedup 1.0000x reference)
//
#include <hip/hip_runtime.h>
#include <hip/hip_bf16.h>
#include <cmath>

// Problem constants
#define B_  16
#define N_  512
#define H_  8
#define F0_ 64
#define DEMB_ 64
#define FIN0_ 131   // 64 + 64 + 3
#define O_  128
#define FIN1_ 1024  // H_*O_

// ---------------------------------------------------------------------------
// x0 build: copy h, instance-norm(emb lookup), instance-norm(user_emb)
// x0 layout: [B*N, 131] = [h(64) | emb(64) | ue(3)]
// ---------------------------------------------------------------------------
__global__ __launch_bounds__(256) void k_copy_h(const float* __restrict__ h,
                                                float* __restrict__ x0) {
    int i = blockIdx.x * 256 + threadIdx.x;   // over B*N*64
    int r = i >> 6, c = i & 63;
    x0[(size_t)r * FIN0_ + c] = h[i];
}

__global__ __launch_bounds__(256) void k_emb_norm(const int* __restrict__ verts,
                                                  const float* __restrict__ table,
                                                  const float* __restrict__ w,
                                                  const float* __restrict__ bb,
                                                  float* __restrict__ x0) {
    int b = blockIdx.x >> 6, c = blockIdx.x & 63;
    int t = threadIdx.x;
    float vals[2], sum = 0.f, sq = 0.f;
#pragma unroll
    for (int i = 0; i < 2; ++i) {
        int n = t + i * 256;
        int vid = verts[b * N_ + n];
        float v = table[(size_t)vid * DEMB_ + c];
        vals[i] = v; sum += v; sq += v * v;
    }
    __shared__ float s0[256], s1[256];
    s0[t] = sum; s1[t] = sq; __syncthreads();
    for (int o = 128; o > 0; o >>= 1) {
        if (t < o) { s0[t] += s0[t + o]; s1[t] += s1[t + o]; }
        __syncthreads();
    }
    float mu = s0[0] * (1.f / N_);
    float var = s1[0] * (1.f / N_) - mu * mu;
    float inv = rsqrtf(var + 1e-5f);
    float ww = w[c], bv = bb[c];
#pragma unroll
    for (int i = 0; i < 2; ++i) {
        int n = t + i * 256;
        x0[((size_t)b * N_ + n) * FIN0_ + 64 + c] = (vals[i] - mu) * inv * ww + bv;
    }
}

__global__ __launch_bounds__(256) void k_ue_norm(const float* __restrict__ ue,
                                                 const float* __restrict__ w,
                                                 const float* __restrict__ bb,
                                                 float* __restrict__ x0) {
    int b = blockIdx.x / 3, c = blockIdx.x % 3;
    int t = threadIdx.x;
    float vals[2], sum = 0.f, sq = 0.f;
#pragma unroll
    for (int i = 0; i < 2; ++i) {
        int n = t + i * 256;
        float v = ue[((size_t)b * N_ + n) * 3 + c];
        vals[i] = v; sum += v; sq += v * v;
    }
    __shared__ float s0[256], s1[256];
    s0[t] = sum; s1[t] = sq; __syncthreads();
    for (int o = 128; o > 0; o >>= 1) {
        if (t < o) { s0[t] += s0[t + o]; s1[t] += s1[t + o]; }
        __syncthreads();
    }
    float mu = s0[0] * (1.f / N_);
    float var = s1[0] * (1.f / N_) - mu * mu;
    float inv = rsqrtf(var + 1e-5f);
    float ww = w[c], bv = bb[c];
#pragma unroll
    for (int i = 0; i < 2; ++i) {
        int n = t + i * 256;
        x0[((size_t)b * N_ + n) * FIN0_ + 128 + c] = (vals[i] - mu) * inv * ww + bv;
    }
}

// ---------------------------------------------------------------------------
// hp = einsum('bnf,hfo->bhno', x, w).  x: [8192, FIN], w: [H, FIN, 128].
// One block: (head, 16-row tile), 128 threads (o). Stage x tile in LDS.
// hp layout: [((b*8+h)*512+n)*128 + o]
// ---------------------------------------------------------------------------
template <int FIN, int FCH>
__global__ __launch_bounds__(128) void k_hp(const float* __restrict__ x,
                                            const float* __restrict__ w,
                                            float* __restrict__ hp) {
    __shared__ float xs[16][FCH];
    int bid = blockIdx.x;
    int hh = bid & 7;
    int r0 = (bid >> 3) * 16;
    int t = threadIdx.x;
    float acc[16];
#pragma unroll
    for (int i = 0; i < 16; ++i) acc[i] = 0.f;
    const float* wh = w + (size_t)hh * FIN * O_;
    for (int f0 = 0; f0 < FIN; f0 += FCH) {
        for (int idx = t; idx < 16 * FCH; idx += 128) {
            int i = idx / FCH, f = idx % FCH;
            xs[i][f] = x[(size_t)(r0 + i) * FIN + f0 + f];
        }
        __syncthreads();
        for (int f = 0; f < FCH; ++f) {
            float wv = wh[(size_t)(f0 + f) * O_ + t];
#pragma unroll
            for (int i = 0; i < 16; ++i) acc[i] += xs[i][f] * wv;
        }
        __syncthreads();
    }
#pragma unroll
    for (int i = 0; i < 16; ++i) {
        int r = r0 + i;
        int b = r >> 9, n = r & 511;
        hp[((size_t)(b * H_ + hh) * N_ + n) * O_ + t] = acc[i];
    }
}

// ---------------------------------------------------------------------------
// s[row] = sum_o tanh(hp[row,o])*a_src[h,o];  d likewise.  row = (b*8+h)*512+n
// 4 rows per 256-thread block, one wave per row.
// ---------------------------------------------------------------------------
__global__ __launch_bounds__(256) void k_sd(const float* __restrict__ hp,
                                            const float* __restrict__ asrc,
                                            const float* __restrict__ adst,
                                            float* __restrict__ s,
                                            float* __restrict__ d) {
    int t = threadIdx.x;
    int w = t >> 6, l = t & 63;
    int row = blockIdx.x * 4 + w;
    int hh = (row >> 9) & 7;
    const float* hr = hp + (size_t)row * O_;
    float sv = 0.f, dv = 0.f;
#pragma unroll
    for (int i = 0; i < 2; ++i) {
        int o = l + i * 64;
        float v = tanhf(hr[o]);
        sv += v * asrc[hh * O_ + o];
        dv += v * adst[hh * O_ + o];
    }
#pragma unroll
    for (int off = 32; off > 0; off >>= 1) {
        sv += __shfl_down(sv, off);
        dv += __shfl_down(dv, off);
    }
    if (l == 0) { s[row] = sv; d[row] = dv; }
}

// ---------------------------------------------------------------------------
// Fused masked softmax + PV.  Block: (b, h, 8-row tile), 128 threads (o).
// Layer0 (L0=true): out = x1[b,n, h*128+o] = elu(pv)
// Layer1 (L0=false): out = o1[((b*8+h)*512+n)*128+o] = pv
// ---------------------------------------------------------------------------
template <bool L0>
__global__ __launch_bounds__(128) void k_attn_pv(const float* __restrict__ hp,
                                                 const float* __restrict__ s,
                                                 const float* __restrict__ dvec,
                                                 const float* __restrict__ adj,
                                                 float* __restrict__ out) {
    int bid = blockIdx.x;
    int nt = bid & 63;          // 64 row-tiles of 8
    int bh = bid >> 6;          // b*8+h
    int b = bh >> 3, hh = bh & 7;
    int n0 = nt * 8;
    int t = threadIdx.x;

    __shared__ float p[8][512];
    __shared__ float sd[512];
    __shared__ float red[4];

    const float* adjb = adj + ((size_t)b * N_ + n0) * N_;
    const float* dd = dvec + (size_t)bh * N_;
    const float* sb = s + (size_t)bh * N_;

    for (int m = t; m < 512; m += 128) sd[m] = dd[m];
    __syncthreads();

    for (int r = 0; r < 8; ++r) {
        float sv = sb[n0 + r];
        float lv[4];
        float lmax = -1e30f;
#pragma unroll
        for (int i = 0; i < 4; ++i) {
            int m = t + i * 128;
            float l = sv + sd[m];
            l = (l >= 0.f) ? l : 0.2f * l;
            l = (adjb[(size_t)r * N_ + m] > 0.f) ? l : -1e30f;
            lv[i] = l;
            lmax = fmaxf(lmax, l);
        }
#pragma unroll
        for (int off = 32; off > 0; off >>= 1) lmax = fmaxf(lmax, __shfl_down(lmax, off));
        if ((t & 63) == 0) red[t >> 6] = lmax;
        __syncthreads();
        float rmax = fmaxf(red[0], red[1]);
        float lsum = 0.f;
#pragma unroll
        for (int i = 0; i < 4; ++i) {
            float e = __expf(lv[i] - rmax);
            lv[i] = e;
            lsum += e;
        }
#pragma unroll
        for (int off = 32; off > 0; off >>= 1) lsum += __shfl_down(lsum, off);
        if ((t & 63) == 0) red[2 + (t >> 6)] = lsum;
        __syncthreads();
        float inv = 1.f / (red[2] + red[3]);
#pragma unroll
        for (int i = 0; i < 4; ++i) p[r][t + i * 128] = lv[i] * inv;
        __syncthreads();
    }

    const float* hpb = hp + (size_t)bh * (N_ * O_);
    float acc[8];
#pragma unroll
    for (int r = 0; r < 8; ++r) acc[r] = 0.f;
    for (int m4 = 0; m4 < 512; m4 += 4) {
        float4 pr[8];
#pragma unroll
        for (int r = 0; r < 8; ++r) pr[r] = *(const float4*)&p[r][m4];
#pragma unroll
        for (int j = 0; j < 4; ++j) {
            float hv = hpb[(size_t)(m4 + j) * O_ + t];
#pragma unroll
            for (int r = 0; r < 8; ++r) acc[r] += ((const float*)&pr[r])[j] * hv;
        }
    }

    if (L0) {
        float* xout = out + ((size_t)b * N_ + n0) * FIN1_ + hh * O_ + t;
#pragma unroll
        for (int r = 0; r < 8; ++r) {
            float v = acc[r];
            v = (v > 0.f) ? v : expm1f(v);
            xout[(size_t)r * FIN1_] = v;
        }
    } else {
        float* oo = out + ((size_t)bh * N_ + n0) * O_ + t;
#pragma unroll
        for (int r = 0; r < 8; ++r) oo[(size_t)r * O_] = acc[r];
    }
}

// ---------------------------------------------------------------------------
// mean over heads + log_softmax over channels(128)
// ---------------------------------------------------------------------------
__global__ __launch_bounds__(128) void k_out(const float* __restrict__ o1,
                                             float* __restrict__ out) {
    int row = blockIdx.x;       // b*512+n
    int b = row >> 9, n = row & 511;
    int t = threadIdx.x;
    float v = 0.f;
#pragma unroll
    for (int hh = 0; hh < H_; ++hh)
        v += o1[((size_t)(b * H_ + hh) * N_ + n) * O_ + t];
    v *= 0.125f;
    float m = v;
#pragma unroll
    for (int off = 32; off > 0; off >>= 1) m = fmaxf(m, __shfl_down(m, off));
    __shared__ float red[4];
    if ((t & 63) == 0) red[t >> 6] = m;
    __syncthreads();
    float rm = fmaxf(red[0], red[1]);
    float e = __expf(v - rm);
    float ss = e;
#pragma unroll
    for (int off = 32; off > 0; off >>= 1) ss += __shfl_down(ss, off);
    if ((t & 63) == 0) red[2 + (t >> 6)] = ss;
    __syncthreads();
    float rs = red[2] + red[3];
    out[(size_t)row * O_ + t] = v - rm - logf(rs);
}

// ---------------------------------------------------------------------------
extern "C" void kernel_launch(void* const* d_in, const int* in_sizes, int n_in,
                              void* d_out, int out_size, void* d_ws, size_t ws_size,
                              hipStream_t stream) {
    const int*   verts = (const int*)d_in[0];
    const float* adj   = (const float*)d_in[1];
    const float* h     = (const float*)d_in[2];
    const float* ue    = (const float*)d_in[3];
    const float* table = (const float*)d_in[4];
    const float* n1w   = (const float*)d_in[5];
    const float* n1b   = (const float*)d_in[6];
    const float* n2w   = (const float*)d_in[7];
    const float* n2b   = (const float*)d_in[8];
    const float* w0    = (const float*)d_in[9];
    const float* as0   = (const float*)d_in[10];
    const float* ad0   = (const float*)d_in[11];
    const float* w1    = (const float*)d_in[12];
    const float* as1   = (const float*)d_in[13];
    const float* ad1   = (const float*)d_in[14];
    float* out = (float*)d_out;

    // workspace layout (floats)
    float* x0 = (float*)d_ws;               // 8192*131   = 1,073,152
    float* hp = x0 + 1073152;               // 16*8*512*128 = 8,388,608 (hp0 then hp1)
    float* x1 = hp + 8388608;               // 8192*1024  = 8,388,608 (x1, then out1)
    float* sb = x1 + 8388608;               // 65,536
    float* db = sb + 65536;                 // 65,536

    hipLaunchKernelGGL(k_copy_h,   dim3(2048), dim3(256), 0, stream, h, x0);
    hipLaunchKernelGGL(k_emb_norm, dim3(1024), dim3(256), 0, stream, verts, table, n1w, n1b, x0);
    hipLaunchKernelGGL(k_ue_norm,  dim3(48),   dim3(256), 0, stream, ue, n2w, n2b, x0);

    // layer 0
    hipLaunchKernelGGL((k_hp<FIN0_, FIN0_>), dim3(4096), dim3(128), 0, stream, x0, w0, hp);
    hipLaunchKernelGGL(k_sd, dim3(16384), dim3(256), 0, stream, hp, as0, ad0, sb, db);
    hipLaunchKernelGGL((k_attn_pv<true>), dim3(8192), dim3(128), 0, stream, hp, sb, db, adj, x1);

    // layer 1
    hipLaunchKernelGGL((k_hp<FIN1_, 128>), dim3(4096), dim3(128), 0, stream, x1, w1, hp);
    hipLaunchKernelGGL(k_sd, dim3(16384), dim3(256), 0, stream, hp, as1, ad1, sb, db);
    hipLaunchKernelGGL((k_attn_pv<false>), dim3(8192), dim3(128), 0, stream, hp, sb, db, adj, x1);

    // mean over heads + log_softmax
    hipLaunchKernelGGL(k_out, dim3(8192), dim3(128), 0, stream, x1, out);
}

// Round 2
// 515.516 us; speedup vs baseline: 1.7222x; 1.7222x over previous
//
#include <hip/hip_runtime.h>
#include <hip/hip_bf16.h>
#include <cmath>

// Problem constants
#define B_  16
#define N_  512
#define H_  8
#define F0_ 64
#define DEMB_ 64
#define FIN0_ 131   // 64 + 64 + 3
#define KP0_ 192    // padded K for layer-0 GEMM
#define O_  128
#define FIN1_ 1024  // H_*O_

typedef __attribute__((ext_vector_type(4))) float f32x4;
typedef __attribute__((ext_vector_type(8))) short bf16x8;

__device__ inline ushort f2bf(float f) {
    union { float f; unsigned u; } x; x.f = f;
    unsigned r = x.u + 0x7fff + ((x.u >> 16) & 1);   // RNE
    return (ushort)(r >> 16);
}
__device__ inline float bf2f(ushort u) {
    union { unsigned u; float f; } x; x.u = ((unsigned)u) << 16;
    return x.f;
}

// ---------------------------------------------------------------------------
// x0p build (bf16, [8192][192], zero-padded cols 131..191 via memset)
// ---------------------------------------------------------------------------
__global__ __launch_bounds__(256) void k_copy_h(const float* __restrict__ h,
                                                ushort* __restrict__ x0) {
    int i = blockIdx.x * 256 + threadIdx.x;   // over B*N*64
    int r = i >> 6, c = i & 63;
    x0[(size_t)r * KP0_ + c] = f2bf(h[i]);
}

__global__ __launch_bounds__(256) void k_emb_norm(const int* __restrict__ verts,
                                                  const float* __restrict__ table,
                                                  const float* __restrict__ w,
                                                  const float* __restrict__ bb,
                                                  ushort* __restrict__ x0) {
    int b = blockIdx.x >> 6, c = blockIdx.x & 63;
    int t = threadIdx.x;
    float vals[2], sum = 0.f, sq = 0.f;
#pragma unroll
    for (int i = 0; i < 2; ++i) {
        int n = t + i * 256;
        int vid = verts[b * N_ + n];
        float v = table[(size_t)vid * DEMB_ + c];
        vals[i] = v; sum += v; sq += v * v;
    }
    __shared__ float s0[256], s1[256];
    s0[t] = sum; s1[t] = sq; __syncthreads();
    for (int o = 128; o > 0; o >>= 1) {
        if (t < o) { s0[t] += s0[t + o]; s1[t] += s1[t + o]; }
        __syncthreads();
    }
    float mu = s0[0] * (1.f / N_);
    float var = s1[0] * (1.f / N_) - mu * mu;
    float inv = rsqrtf(var + 1e-5f);
    float ww = w[c], bv = bb[c];
#pragma unroll
    for (int i = 0; i < 2; ++i) {
        int n = t + i * 256;
        x0[((size_t)b * N_ + n) * KP0_ + 64 + c] = f2bf((vals[i] - mu) * inv * ww + bv);
    }
}

__global__ __launch_bounds__(256) void k_ue_norm(const float* __restrict__ ue,
                                                 const float* __restrict__ w,
                                                 const float* __restrict__ bb,
                                                 ushort* __restrict__ x0) {
    int b = blockIdx.x / 3, c = blockIdx.x % 3;
    int t = threadIdx.x;
    float vals[2], sum = 0.f, sq = 0.f;
#pragma unroll
    for (int i = 0; i < 2; ++i) {
        int n = t + i * 256;
        float v = ue[((size_t)b * N_ + n) * 3 + c];
        vals[i] = v; sum += v; sq += v * v;
    }
    __shared__ float s0[256], s1[256];
    s0[t] = sum; s1[t] = sq; __syncthreads();
    for (int o = 128; o > 0; o >>= 1) {
        if (t < o) { s0[t] += s0[t + o]; s1[t] += s1[t + o]; }
        __syncthreads();
    }
    float mu = s0[0] * (1.f / N_);
    float var = s1[0] * (1.f / N_) - mu * mu;
    float inv = rsqrtf(var + 1e-5f);
    float ww = w[c], bv = bb[c];
#pragma unroll
    for (int i = 0; i < 2; ++i) {
        int n = t + i * 256;
        x0[((size_t)b * N_ + n) * KP0_ + 128 + c] = f2bf((vals[i] - mu) * inv * ww + bv);
    }
}

// ---------------------------------------------------------------------------
// Weight transpose+convert: w [H][K][128] f32 -> wt [H][128][Kp] bf16 (pad 0)
// grid = H * (Kp/8), block = 128 (o). Each thread emits one bf16x8.
// ---------------------------------------------------------------------------
template <int K, int Kp>
__global__ __launch_bounds__(128) void k_wt(const float* __restrict__ w,
                                            ushort* __restrict__ wt) {
    int hh = blockIdx.x / (Kp / 8);
    int kc = blockIdx.x % (Kp / 8);
    int o = threadIdx.x;
    bf16x8 v;
#pragma unroll
    for (int j = 0; j < 8; ++j) {
        int k = kc * 8 + j;
        float f = (k < K) ? w[((size_t)hh * K + k) * 128 + o] : 0.f;
        v[j] = (short)f2bf(f);
    }
    *(bf16x8*)(wt + ((size_t)(hh * 128 + o)) * Kp + kc * 8) = v;
}

// ---------------------------------------------------------------------------
// MFMA GEMM: hp[b,h,n,o] = sum_k A[r=b*512+n][k] * Wt[h][o][k]   (both bf16)
// Tile 128x128 (BN = full O), BK=64, 4 waves (2x2 of 64x64), XOR-swizzled LDS,
// global_load_lds width-16 staging with pre-swizzled global source.
// ---------------------------------------------------------------------------
template <int K>
__global__ __launch_bounds__(256) void k_gemm(const ushort* __restrict__ A,
                                              const ushort* __restrict__ Wt,
                                              float* __restrict__ hp) {
    __shared__ ushort As[128 * 64];
    __shared__ ushort Bs[128 * 64];
    int bid = blockIdx.x;
    int hh = bid >> 6;           // head
    int mt = bid & 63;           // 128-row tile of M=8192
    int tid = threadIdx.x;
    int wid = tid >> 6, l = tid & 63;
    int wm = wid >> 1, wn = wid & 1;

    const ushort* Ab = A + (size_t)mt * 128 * K;
    const ushort* Wb = Wt + (size_t)hh * 128 * K;

    f32x4 acc[4][4];
#pragma unroll
    for (int m = 0; m < 4; ++m)
#pragma unroll
        for (int n = 0; n < 4; ++n) acc[m][n] = (f32x4){0.f, 0.f, 0.f, 0.f};

    int srow = tid >> 3;         // 0..31 (row within 32-row stage slab)
    int segp = tid & 7;          // physical 16B slot

    for (int kt = 0; kt < K / 64; ++kt) {
        int k0 = kt * 64;
#pragma unroll
        for (int it = 0; it < 4; ++it) {
            int row = it * 32 + srow;
            int segl = segp ^ (row & 7);             // inverse-swizzled source
            // wave-uniform LDS base: (it*32 + wid*8) rows of 64 ushorts
            __builtin_amdgcn_global_load_lds(
                (const __attribute__((address_space(1))) void*)(Ab + (size_t)row * K + k0 + segl * 8),
                (__attribute__((address_space(3))) void*)(As + (it * 32 + wid * 8) * 64),
                16, 0, 0);
            __builtin_amdgcn_global_load_lds(
                (const __attribute__((address_space(1))) void*)(Wb + (size_t)row * K + k0 + segl * 8),
                (__attribute__((address_space(3))) void*)(Bs + (it * 32 + wid * 8) * 64),
                16, 0, 0);
        }
        __syncthreads();

        int lr = l & 15;
        int kg = l >> 4;
#pragma unroll
        for (int kk = 0; kk < 2; ++kk) {
            int segl = kk * 4 + kg;
            bf16x8 a[4], b[4];
#pragma unroll
            for (int m = 0; m < 4; ++m) {
                int row = wm * 64 + m * 16 + lr;
                int sp = segl ^ (row & 7);
                a[m] = *(const bf16x8*)(As + row * 64 + sp * 8);
            }
#pragma unroll
            for (int n = 0; n < 4; ++n) {
                int row = wn * 64 + n * 16 + lr;
                int sp = segl ^ (row & 7);
                b[n] = *(const bf16x8*)(Bs + row * 64 + sp * 8);
            }
#pragma unroll
            for (int m = 0; m < 4; ++m)
#pragma unroll
                for (int n = 0; n < 4; ++n)
                    acc[m][n] = __builtin_amdgcn_mfma_f32_16x16x32_bf16(a[m], b[n], acc[m][n], 0, 0, 0);
        }
        __syncthreads();
    }

    // epilogue: C/D layout col=lane&15, row=(lane>>4)*4+reg
    int b = mt >> 2;
    int nn0 = (mt & 3) * 128;
    float* Hp = hp + ((size_t)(b * H_ + hh) * N_ + nn0) * O_;
#pragma unroll
    for (int m = 0; m < 4; ++m)
#pragma unroll
        for (int n = 0; n < 4; ++n)
#pragma unroll
            for (int j = 0; j < 4; ++j) {
                int rr = wm * 64 + m * 16 + (l >> 4) * 4 + j;
                int cc = wn * 64 + n * 16 + (l & 15);
                Hp[(size_t)rr * O_ + cc] = acc[m][n][j];
            }
}

// ---------------------------------------------------------------------------
// s[row] = sum_o tanh(hp[row,o])*a_src[h,o];  d likewise.  row = (b*8+h)*512+n
// ---------------------------------------------------------------------------
__global__ __launch_bounds__(256) void k_sd(const float* __restrict__ hp,
                                            const float* __restrict__ asrc,
                                            const float* __restrict__ adst,
                                            float* __restrict__ s,
                                            float* __restrict__ d) {
    int t = threadIdx.x;
    int w = t >> 6, l = t & 63;
    int row = blockIdx.x * 4 + w;
    int hh = (row >> 9) & 7;
    const float* hr = hp + (size_t)row * O_;
    float sv = 0.f, dv = 0.f;
#pragma unroll
    for (int i = 0; i < 2; ++i) {
        int o = l + i * 64;
        float v = tanhf(hr[o]);
        sv += v * asrc[hh * O_ + o];
        dv += v * adst[hh * O_ + o];
    }
#pragma unroll
    for (int off = 32; off > 0; off >>= 1) {
        sv += __shfl_down(sv, off);
        dv += __shfl_down(dv, off);
    }
    if (l == 0) { s[row] = sv; d[row] = dv; }
}

// ---------------------------------------------------------------------------
// Fused masked softmax + PV (fp32 VALU).  Output bf16:
//  L0: x1bf[b,n, h*128+o] = elu(pv)        L1: o1[((b*8+h)*512+n)*128+o] = pv
// ---------------------------------------------------------------------------
template <bool L0>
__global__ __launch_bounds__(128) void k_attn_pv(const float* __restrict__ hp,
                                                 const float* __restrict__ s,
                                                 const float* __restrict__ dvec,
                                                 const float* __restrict__ adj,
                                                 ushort* __restrict__ out) {
    int bid = blockIdx.x;
    int nt = bid & 63;
    int bh = bid >> 6;
    int b = bh >> 3, hh = bh & 7;
    int n0 = nt * 8;
    int t = threadIdx.x;

    __shared__ float p[8][512];
    __shared__ float sd[512];
    __shared__ float red[4];

    const float* adjb = adj + ((size_t)b * N_ + n0) * N_;
    const float* dd = dvec + (size_t)bh * N_;
    const float* sb = s + (size_t)bh * N_;

    for (int m = t; m < 512; m += 128) sd[m] = dd[m];
    __syncthreads();

    for (int r = 0; r < 8; ++r) {
        float sv = sb[n0 + r];
        float lv[4];
        float lmax = -1e30f;
#pragma unroll
        for (int i = 0; i < 4; ++i) {
            int m = t + i * 128;
            float l = sv + sd[m];
            l = (l >= 0.f) ? l : 0.2f * l;
            l = (adjb[(size_t)r * N_ + m] > 0.f) ? l : -1e30f;
            lv[i] = l;
            lmax = fmaxf(lmax, l);
        }
#pragma unroll
        for (int off = 32; off > 0; off >>= 1) lmax = fmaxf(lmax, __shfl_down(lmax, off));
        if ((t & 63) == 0) red[t >> 6] = lmax;
        __syncthreads();
        float rmax = fmaxf(red[0], red[1]);
        float lsum = 0.f;
#pragma unroll
        for (int i = 0; i < 4; ++i) {
            float e = __expf(lv[i] - rmax);
            lv[i] = e;
            lsum += e;
        }
#pragma unroll
        for (int off = 32; off > 0; off >>= 1) lsum += __shfl_down(lsum, off);
        if ((t & 63) == 0) red[2 + (t >> 6)] = lsum;
        __syncthreads();
        float inv = 1.f / (red[2] + red[3]);
#pragma unroll
        for (int i = 0; i < 4; ++i) p[r][t + i * 128] = lv[i] * inv;
        __syncthreads();
    }

    const float* hpb = hp + (size_t)bh * (N_ * O_);
    float acc[8];
#pragma unroll
    for (int r = 0; r < 8; ++r) acc[r] = 0.f;
    for (int m4 = 0; m4 < 512; m4 += 4) {
        float4 pr[8];
#pragma unroll
        for (int r = 0; r < 8; ++r) pr[r] = *(const float4*)&p[r][m4];
#pragma unroll
        for (int j = 0; j < 4; ++j) {
            float hv = hpb[(size_t)(m4 + j) * O_ + t];
#pragma unroll
            for (int r = 0; r < 8; ++r) acc[r] += ((const float*)&pr[r])[j] * hv;
        }
    }

    if (L0) {
        ushort* xout = out + ((size_t)b * N_ + n0) * FIN1_ + hh * O_ + t;
#pragma unroll
        for (int r = 0; r < 8; ++r) {
            float v = acc[r];
            v = (v > 0.f) ? v : expm1f(v);
            xout[(size_t)r * FIN1_] = f2bf(v);
        }
    } else {
        ushort* oo = out + ((size_t)bh * N_ + n0) * O_ + t;
#pragma unroll
        for (int r = 0; r < 8; ++r) oo[(size_t)r * O_] = f2bf(acc[r]);
    }
}

// ---------------------------------------------------------------------------
// mean over heads (bf16 in) + log_softmax over channels(128)
// ---------------------------------------------------------------------------
__global__ __launch_bounds__(128) void k_out(const ushort* __restrict__ o1,
                                             float* __restrict__ out) {
    int row = blockIdx.x;       // b*512+n
    int b = row >> 9, n = row & 511;
    int t = threadIdx.x;
    float v = 0.f;
#pragma unroll
    for (int hh = 0; hh < H_; ++hh)
        v += bf2f(o1[((size_t)(b * H_ + hh) * N_ + n) * O_ + t]);
    v *= 0.125f;
    float m = v;
#pragma unroll
    for (int off = 32; off > 0; off >>= 1) m = fmaxf(m, __shfl_down(m, off));
    __shared__ float red[4];
    if ((t & 63) == 0) red[t >> 6] = m;
    __syncthreads();
    float rm = fmaxf(red[0], red[1]);
    float e = __expf(v - rm);
    float ss = e;
#pragma unroll
    for (int off = 32; off > 0; off >>= 1) ss += __shfl_down(ss, off);
    if ((t & 63) == 0) red[2 + (t >> 6)] = ss;
    __syncthreads();
    float rs = red[2] + red[3];
    out[(size_t)row * O_ + t] = v - rm - logf(rs);
}

// ---------------------------------------------------------------------------
extern "C" void kernel_launch(void* const* d_in, const int* in_sizes, int n_in,
                              void* d_out, int out_size, void* d_ws, size_t ws_size,
                              hipStream_t stream) {
    const int*   verts = (const int*)d_in[0];
    const float* adj   = (const float*)d_in[1];
    const float* h     = (const float*)d_in[2];
    const float* ue    = (const float*)d_in[3];
    const float* table = (const float*)d_in[4];
    const float* n1w   = (const float*)d_in[5];
    const float* n1b   = (const float*)d_in[6];
    const float* n2w   = (const float*)d_in[7];
    const float* n2b   = (const float*)d_in[8];
    const float* w0    = (const float*)d_in[9];
    const float* as0   = (const float*)d_in[10];
    const float* ad0   = (const float*)d_in[11];
    const float* w1    = (const float*)d_in[12];
    const float* as1   = (const float*)d_in[13];
    const float* ad1   = (const float*)d_in[14];
    float* out = (float*)d_out;

    // workspace layout (o1 region overlaps x0p/wt0/wt1, which are dead by
    // the time o1 is written)
    ushort* o1  = (ushort*)d_ws;                  // 8,388,608 u (16.8 MB)
    ushort* x0p = (ushort*)d_ws;                  // 8192*192 = 1,572,864 u
    ushort* wt0 = x0p + 1572864;                  // 8*128*192 = 196,608 u
    ushort* wt1 = wt0 + 196608;                   // 8*128*1024 = 1,048,576 u
    float*  hp  = (float*)((char*)d_ws + (size_t)8388608 * sizeof(ushort));
    ushort* x1bf = (ushort*)(hp + 8388608);       // 8,388,608 u
    float*  sb  = (float*)(x1bf + 8388608);       // 65,536 f
    float*  db  = sb + 65536;                     // 65,536 f

    hipMemsetAsync(x0p, 0, (size_t)8192 * KP0_ * sizeof(ushort), stream);
    hipLaunchKernelGGL(k_copy_h,   dim3(2048), dim3(256), 0, stream, h, x0p);
    hipLaunchKernelGGL(k_emb_norm, dim3(1024), dim3(256), 0, stream, verts, table, n1w, n1b, x0p);
    hipLaunchKernelGGL(k_ue_norm,  dim3(48),   dim3(256), 0, stream, ue, n2w, n2b, x0p);
    hipLaunchKernelGGL((k_wt<FIN0_, KP0_>), dim3(8 * (KP0_ / 8)), dim3(128), 0, stream, w0, wt0);
    hipLaunchKernelGGL((k_wt<FIN1_, FIN1_>), dim3(8 * (FIN1_ / 8)), dim3(128), 0, stream, w1, wt1);

    // layer 0
    hipLaunchKernelGGL((k_gemm<KP0_>), dim3(512), dim3(256), 0, stream, x0p, wt0, hp);
    hipLaunchKernelGGL(k_sd, dim3(16384), dim3(256), 0, stream, hp, as0, ad0, sb, db);
    hipLaunchKernelGGL((k_attn_pv<true>), dim3(8192), dim3(128), 0, stream, hp, sb, db, adj, x1bf);

    // layer 1
    hipLaunchKernelGGL((k_gemm<FIN1_>), dim3(512), dim3(256), 0, stream, x1bf, wt1, hp);
    hipLaunchKernelGGL(k_sd, dim3(16384), dim3(256), 0, stream, hp, as1, ad1, sb, db);
    hipLaunchKernelGGL((k_attn_pv<false>), dim3(8192), dim3(128), 0, stream, hp, sb, db, adj, o1);

    // mean over heads + log_softmax
    hipLaunchKernelGGL(k_out, dim3(8192), dim3(128), 0, stream, o1, out);
}

// Round 3
// 211.633 us; speedup vs baseline: 4.1951x; 2.4359x over previous
//
#include <hip/hip_runtime.h>
#include <hip/hip_bf16.h>
#include <cmath>

// Problem constants
#define B_  16
#define N_  512
#define H_  8
#define F0_ 64
#define DEMB_ 64
#define FIN0_ 131   // 64 + 64 + 3
#define KP0_ 192    // padded K for layer-0 GEMM
#define O_  128
#define FIN1_ 1024  // H_*O_

typedef __attribute__((ext_vector_type(4))) float f32x4;
typedef __attribute__((ext_vector_type(8))) short bf16x8;

__device__ inline ushort f2bf(float f) {
    union { float f; unsigned u; } x; x.f = f;
    unsigned r = x.u + 0x7fff + ((x.u >> 16) & 1);   // RNE
    return (ushort)(r >> 16);
}
__device__ inline float bf2f(ushort u) {
    union { unsigned u; float f; } x; x.u = ((unsigned)u) << 16;
    return x.f;
}
__device__ inline float tanh_fast(float x) {
    x = fminf(fmaxf(x, -15.f), 15.f);
    float e = __expf(2.f * x);
    return (e - 1.f) * __frcp_rn(e + 1.f);
}

// ---------------------------------------------------------------------------
// x0p build (bf16, [8192][192], zero-padded cols 131..191 via memset)
// ---------------------------------------------------------------------------
__global__ __launch_bounds__(256) void k_copy_h(const float* __restrict__ h,
                                                ushort* __restrict__ x0) {
    int i = blockIdx.x * 256 + threadIdx.x;   // over B*N*64
    int r = i >> 6, c = i & 63;
    x0[(size_t)r * KP0_ + c] = f2bf(h[i]);
}

__global__ __launch_bounds__(256) void k_emb_norm(const int* __restrict__ verts,
                                                  const float* __restrict__ table,
                                                  const float* __restrict__ w,
                                                  const float* __restrict__ bb,
                                                  ushort* __restrict__ x0) {
    int b = blockIdx.x >> 6, c = blockIdx.x & 63;
    int t = threadIdx.x;
    float vals[2], sum = 0.f, sq = 0.f;
#pragma unroll
    for (int i = 0; i < 2; ++i) {
        int n = t + i * 256;
        int vid = verts[b * N_ + n];
        float v = table[(size_t)vid * DEMB_ + c];
        vals[i] = v; sum += v; sq += v * v;
    }
    __shared__ float s0[256], s1[256];
    s0[t] = sum; s1[t] = sq; __syncthreads();
    for (int o = 128; o > 0; o >>= 1) {
        if (t < o) { s0[t] += s0[t + o]; s1[t] += s1[t + o]; }
        __syncthreads();
    }
    float mu = s0[0] * (1.f / N_);
    float var = s1[0] * (1.f / N_) - mu * mu;
    float inv = rsqrtf(var + 1e-5f);
    float ww = w[c], bv = bb[c];
#pragma unroll
    for (int i = 0; i < 2; ++i) {
        int n = t + i * 256;
        x0[((size_t)b * N_ + n) * KP0_ + 64 + c] = f2bf((vals[i] - mu) * inv * ww + bv);
    }
}

__global__ __launch_bounds__(256) void k_ue_norm(const float* __restrict__ ue,
                                                 const float* __restrict__ w,
                                                 const float* __restrict__ bb,
                                                 ushort* __restrict__ x0) {
    int b = blockIdx.x / 3, c = blockIdx.x % 3;
    int t = threadIdx.x;
    float vals[2], sum = 0.f, sq = 0.f;
#pragma unroll
    for (int i = 0; i < 2; ++i) {
        int n = t + i * 256;
        float v = ue[((size_t)b * N_ + n) * 3 + c];
        vals[i] = v; sum += v; sq += v * v;
    }
    __shared__ float s0[256], s1[256];
    s0[t] = sum; s1[t] = sq; __syncthreads();
    for (int o = 128; o > 0; o >>= 1) {
        if (t < o) { s0[t] += s0[t + o]; s1[t] += s1[t + o]; }
        __syncthreads();
    }
    float mu = s0[0] * (1.f / N_);
    float var = s1[0] * (1.f / N_) - mu * mu;
    float inv = rsqrtf(var + 1e-5f);
    float ww = w[c], bv = bb[c];
#pragma unroll
    for (int i = 0; i < 2; ++i) {
        int n = t + i * 256;
        x0[((size_t)b * N_ + n) * KP0_ + 128 + c] = f2bf((vals[i] - mu) * inv * ww + bv);
    }
}

// ---------------------------------------------------------------------------
// Weight transpose+convert: w [H][K][128] f32 -> wt [H][128][Kp] bf16 (pad 0)
// ---------------------------------------------------------------------------
template <int K, int Kp>
__global__ __launch_bounds__(128) void k_wt(const float* __restrict__ w,
                                            ushort* __restrict__ wt) {
    int hh = blockIdx.x / (Kp / 8);
    int kc = blockIdx.x % (Kp / 8);
    int o = threadIdx.x;
    bf16x8 v;
#pragma unroll
    for (int j = 0; j < 8; ++j) {
        int k = kc * 8 + j;
        float f = (k < K) ? w[((size_t)hh * K + k) * 128 + o] : 0.f;
        v[j] = (short)f2bf(f);
    }
    *(bf16x8*)(wt + ((size_t)(hh * 128 + o)) * Kp + kc * 8) = v;
}

// ---------------------------------------------------------------------------
// adj > 0 bitmask: word (b*512+n)*8 + c holds bits for m = c*64 .. c*64+63
// ---------------------------------------------------------------------------
__global__ __launch_bounds__(256) void k_mask(const float* __restrict__ adj,
                                              unsigned long long* __restrict__ mask) {
    int gid = blockIdx.x * 256 + threadIdx.x;
    float v = adj[gid];
    unsigned long long m = __ballot(v > 0.f);
    if ((threadIdx.x & 63) == 0) mask[gid >> 6] = m;
}

// ---------------------------------------------------------------------------
// MFMA GEMM: hpT[bh][o][n] = sum_k A[b*512+n][k] * Wt[h][o][k]   (bf16 out)
// Tile 128x128, BK=64, 4 waves (2x2 of 64x64), XOR-swizzled LDS,
// global_load_lds width-16 staging with pre-swizzled global source.
// ---------------------------------------------------------------------------
template <int K>
__global__ __launch_bounds__(256) void k_gemm(const ushort* __restrict__ A,
                                              const ushort* __restrict__ Wt,
                                              ushort* __restrict__ hpT) {
    __shared__ ushort As[128 * 64];
    __shared__ ushort Bs[128 * 64];
    int bid = blockIdx.x;
    int hh = bid >> 6;           // head
    int mt = bid & 63;           // 128-row tile of M=8192
    int tid = threadIdx.x;
    int wid = tid >> 6, l = tid & 63;
    int wm = wid >> 1, wn = wid & 1;

    const ushort* Ab = A + (size_t)mt * 128 * K;
    const ushort* Wb = Wt + (size_t)hh * 128 * K;

    f32x4 acc[4][4];
#pragma unroll
    for (int m = 0; m < 4; ++m)
#pragma unroll
        for (int n = 0; n < 4; ++n) acc[m][n] = (f32x4){0.f, 0.f, 0.f, 0.f};

    int srow = tid >> 3;         // 0..31
    int segp = tid & 7;          // physical 16B slot

    for (int kt = 0; kt < K / 64; ++kt) {
        int k0 = kt * 64;
#pragma unroll
        for (int it = 0; it < 4; ++it) {
            int row = it * 32 + srow;
            int segl = segp ^ (row & 7);
            __builtin_amdgcn_global_load_lds(
                (const __attribute__((address_space(1))) void*)(Ab + (size_t)row * K + k0 + segl * 8),
                (__attribute__((address_space(3))) void*)(As + (it * 32 + wid * 8) * 64),
                16, 0, 0);
            __builtin_amdgcn_global_load_lds(
                (const __attribute__((address_space(1))) void*)(Wb + (size_t)row * K + k0 + segl * 8),
                (__attribute__((address_space(3))) void*)(Bs + (it * 32 + wid * 8) * 64),
                16, 0, 0);
        }
        __syncthreads();

        int lr = l & 15;
        int kg = l >> 4;
#pragma unroll
        for (int kk = 0; kk < 2; ++kk) {
            int segl = kk * 4 + kg;
            bf16x8 a[4], b[4];
#pragma unroll
            for (int m = 0; m < 4; ++m) {
                int row = wm * 64 + m * 16 + lr;
                int sp = segl ^ (row & 7);
                a[m] = *(const bf16x8*)(As + row * 64 + sp * 8);
            }
#pragma unroll
            for (int n = 0; n < 4; ++n) {
                int row = wn * 64 + n * 16 + lr;
                int sp = segl ^ (row & 7);
                b[n] = *(const bf16x8*)(Bs + row * 64 + sp * 8);
            }
#pragma unroll
            for (int m = 0; m < 4; ++m)
#pragma unroll
                for (int n = 0; n < 4; ++n)
                    acc[m][n] = __builtin_amdgcn_mfma_f32_16x16x32_bf16(a[m], b[n], acc[m][n], 0, 0, 0);
        }
        __syncthreads();
    }

    // epilogue: D col=lane&15 (o), row=(lane>>4)*4+j (n). Write transposed bf16.
    int bb = mt >> 2;
    int n_in_b = (mt & 3) * 128;
    ushort* Hp = hpT + ((size_t)(bb * H_ + hh) * 128) * 512;
#pragma unroll
    for (int m = 0; m < 4; ++m)
#pragma unroll
        for (int n = 0; n < 4; ++n) {
            int rr = wm * 64 + m * 16 + (l >> 4) * 4;      // node rows (4 consecutive via j)
            int cc = wn * 64 + n * 16 + (l & 15);          // o column
            ushort4 v;
            v.x = f2bf(acc[m][n][0]);
            v.y = f2bf(acc[m][n][1]);
            v.z = f2bf(acc[m][n][2]);
            v.w = f2bf(acc[m][n][3]);
            *(ushort4*)(Hp + (size_t)cc * 512 + n_in_b + rr) = v;
        }
}

// ---------------------------------------------------------------------------
// s[row] = sum_o tanh(hpT[bh][o][row])*a_src[h,o];  d likewise.
// grid: (bh, half), block 128 threads, 2 n per thread (bf16x2 loads).
// ---------------------------------------------------------------------------
__global__ __launch_bounds__(128) void k_sd(const ushort* __restrict__ hpT,
                                            const float* __restrict__ asrc,
                                            const float* __restrict__ adst,
                                            float* __restrict__ s,
                                            float* __restrict__ d) {
    int bid = blockIdx.x;
    int bh = bid >> 1, half = bid & 1;
    int hh = bh & 7;
    int t = threadIdx.x;
    int n = half * 256 + 2 * t;
    const ushort* base = hpT + (size_t)bh * 128 * 512 + n;
    float s0 = 0.f, s1 = 0.f, d0 = 0.f, d1 = 0.f;
    for (int o = 0; o < 128; ++o) {
        unsigned v = *(const unsigned*)(base + (size_t)o * 512);
        float v0 = bf2f((ushort)(v & 0xffff));
        float v1 = bf2f((ushort)(v >> 16));
        float av = asrc[hh * 128 + o], dv = adst[hh * 128 + o];
        float t0 = tanh_fast(v0), t1 = tanh_fast(v1);
        s0 += t0 * av; s1 += t1 * av;
        d0 += t0 * dv; d1 += t1 * dv;
    }
    float2 sv = {s0, s1}, dv2 = {d0, d1};
    *(float2*)(s + (size_t)bh * 512 + n) = sv;
    *(float2*)(d + (size_t)bh * 512 + n) = dv2;
}

// ---------------------------------------------------------------------------
// Fused masked softmax + MFMA PV.
// grid 2048: b = bid&15 (XCD pin), hh = (bid>>4)&7, tile = bid>>7 (32 rows).
// P (unnormalized exp, bf16, XOR-swizzled) in LDS; V^T frags direct from hpT.
// ---------------------------------------------------------------------------
union ShU {
    ushort P[32 * 512];          // 32 KB
    float  T[4 * 32 * 36];       // per-wave transpose staging (18 KB)
};

template <bool L0>
__global__ __launch_bounds__(256, 4) void k_attn(const ushort* __restrict__ hpT,
                                                 const float* __restrict__ sbuf,
                                                 const float* __restrict__ dbuf,
                                                 const unsigned long long* __restrict__ mask,
                                                 ushort* __restrict__ out) {
    __shared__ ShU u;
    __shared__ float ds2[8 * 68];
    __shared__ float rs[32];

    int bid = blockIdx.x;
    int b = bid & 15, hh = (bid >> 4) & 7, tile = bid >> 7;
    int bh = b * 8 + hh;
    int n0 = tile * 32;
    int t = threadIdx.x;
    int wid = t >> 6, l = t & 63;

    // stage d (bank-swizzled: index m + 4*(m>>6))
    for (int m = t; m < 512; m += 256)
        ds2[m + ((m >> 6) << 2)] = dbuf[(size_t)bh * 512 + m];
    __syncthreads();

    // ---- softmax: unnormalized e -> P, rowsum -> rs ----
    int row = t >> 3, c = t & 7;
    float sv = sbuf[(size_t)bh * 512 + n0 + row];
    unsigned long long mb = mask[((size_t)(b * 512 + n0 + row) << 3) + c];
    const float* dsc = ds2 + c * 68;

    float mx = -1e30f;
#pragma unroll
    for (int j = 0; j < 16; ++j) {
        f32x4 d4 = *(const f32x4*)(dsc + j * 4);
#pragma unroll
        for (int q = 0; q < 4; ++q) {
            float lg = sv + d4[q];
            lg = (lg >= 0.f) ? lg : 0.2f * lg;
            lg = ((mb >> (j * 4 + q)) & 1) ? lg : -1e30f;
            mx = fmaxf(mx, lg);
        }
    }
    mx = fmaxf(mx, __shfl_xor(mx, 1));
    mx = fmaxf(mx, __shfl_xor(mx, 2));
    mx = fmaxf(mx, __shfl_xor(mx, 4));

    float sum = 0.f;
#pragma unroll
    for (int j = 0; j < 8; ++j) {
        f32x4 da = *(const f32x4*)(dsc + j * 8);
        f32x4 db2 = *(const f32x4*)(dsc + j * 8 + 4);
        bf16x8 pk;
#pragma unroll
        for (int q = 0; q < 8; ++q) {
            float dm = (q < 4) ? da[q] : db2[q - 4];
            float lg = sv + dm;
            lg = (lg >= 0.f) ? lg : 0.2f * lg;
            lg = ((mb >> (j * 8 + q)) & 1) ? lg : -1e30f;
            float e = __expf(lg - mx);
            sum += e;
            pk[q] = (short)f2bf(e);
        }
        int ba = (row * 1024 + c * 128 + j * 16) ^ ((row & 7) << 4);
        *(bf16x8*)((char*)u.P + ba) = pk;
    }
    sum += __shfl_xor(sum, 1);
    sum += __shfl_xor(sum, 2);
    sum += __shfl_xor(sum, 4);
    if (c == 0) rs[row] = sum;
    __syncthreads();

    // ---- PV: O^T[o 32/wave][n 32] = V^T x P^T via MFMA ----
    int lr = l & 15, lg4 = l >> 4;
    int ob = wid * 32;
    const ushort* Ab = hpT + ((size_t)(bh * 128 + ob + lr)) * 512 + lg4 * 8;
    int xr = (lr & 7) << 4;
    int pb0 = lr * 1024 + lg4 * 16;
    int pb1 = pb0 + 16 * 1024;

    f32x4 acc[2][2];
#pragma unroll
    for (int i = 0; i < 2; ++i)
#pragma unroll
        for (int j = 0; j < 2; ++j) acc[i][j] = (f32x4){0.f, 0.f, 0.f, 0.f};

#pragma unroll
    for (int ks = 0; ks < 16; ++ks) {
        bf16x8 a0 = *(const bf16x8*)(Ab + ks * 32);
        bf16x8 a1 = *(const bf16x8*)(Ab + 16 * 512 + ks * 32);
        bf16x8 b0 = *(const bf16x8*)((const char*)u.P + ((pb0 + ks * 64) ^ xr));
        bf16x8 b1 = *(const bf16x8*)((const char*)u.P + ((pb1 + ks * 64) ^ xr));
        acc[0][0] = __builtin_amdgcn_mfma_f32_16x16x32_bf16(a0, b0, acc[0][0], 0, 0, 0);
        acc[1][0] = __builtin_amdgcn_mfma_f32_16x16x32_bf16(a1, b0, acc[1][0], 0, 0, 0);
        acc[0][1] = __builtin_amdgcn_mfma_f32_16x16x32_bf16(a0, b1, acc[0][1], 0, 0, 0);
        acc[1][1] = __builtin_amdgcn_mfma_f32_16x16x32_bf16(a1, b1, acc[1][1], 0, 0, 0);
    }
    __syncthreads();   // all waves done reading P before T overwrites it

    // normalize + per-wave transpose through LDS
    float rinv0 = __frcp_rn(rs[lr]);
    float rinv1 = __frcp_rn(rs[16 + lr]);
    float* Tw = u.T + wid * (32 * 36);
#pragma unroll
    for (int of = 0; of < 2; ++of)
#pragma unroll
        for (int nf = 0; nf < 2; ++nf) {
            float ri = nf ? rinv1 : rinv0;
#pragma unroll
            for (int j = 0; j < 4; ++j)
                Tw[(nf * 16 + lr) * 36 + of * 16 + lg4 * 4 + j] = acc[of][nf][j] * ri;
        }
    __syncthreads();

    int nr = l >> 1, oh = l & 1;
    ushort* op;
    if (L0)
        op = out + ((size_t)(b * 512 + n0 + nr)) * FIN1_ + hh * 128 + ob + oh * 16;
    else
        op = out + ((size_t)bh * 512 + n0 + nr) * 128 + ob + oh * 16;

    bf16x8 w0v, w1v;
#pragma unroll
    for (int j = 0; j < 4; ++j) {
        f32x4 v = *(const f32x4*)(Tw + nr * 36 + oh * 16 + j * 4);
#pragma unroll
        for (int q = 0; q < 4; ++q) {
            float f = v[q];
            if (L0) f = (f > 0.f) ? f : expm1f(f);
            if (j < 2) w0v[j * 4 + q] = (short)f2bf(f);
            else       w1v[(j - 2) * 4 + q] = (short)f2bf(f);
        }
    }
    *(bf16x8*)op = w0v;
    *(bf16x8*)(op + 8) = w1v;
}

// ---------------------------------------------------------------------------
// mean over heads (bf16 in) + log_softmax over channels(128)
// ---------------------------------------------------------------------------
__global__ __launch_bounds__(128) void k_out(const ushort* __restrict__ o1,
                                             float* __restrict__ out) {
    int row = blockIdx.x;       // b*512+n
    int b = row >> 9, n = row & 511;
    int t = threadIdx.x;
    float v = 0.f;
#pragma unroll
    for (int hh = 0; hh < H_; ++hh)
        v += bf2f(o1[((size_t)(b * H_ + hh) * N_ + n) * O_ + t]);
    v *= 0.125f;
    float m = v;
#pragma unroll
    for (int off = 32; off > 0; off >>= 1) m = fmaxf(m, __shfl_down(m, off));
    __shared__ float red[4];
    if ((t & 63) == 0) red[t >> 6] = m;
    __syncthreads();
    float rm = fmaxf(red[0], red[1]);
    float e = __expf(v - rm);
    float ss = e;
#pragma unroll
    for (int off = 32; off > 0; off >>= 1) ss += __shfl_down(ss, off);
    if ((t & 63) == 0) red[2 + (t >> 6)] = ss;
    __syncthreads();
    float rs2 = red[2] + red[3];
    out[(size_t)row * O_ + t] = v - rm - logf(rs2);
}

// ---------------------------------------------------------------------------
extern "C" void kernel_launch(void* const* d_in, const int* in_sizes, int n_in,
                              void* d_out, int out_size, void* d_ws, size_t ws_size,
                              hipStream_t stream) {
    const int*   verts = (const int*)d_in[0];
    const float* adj   = (const float*)d_in[1];
    const float* h     = (const float*)d_in[2];
    const float* ue    = (const float*)d_in[3];
    const float* table = (const float*)d_in[4];
    const float* n1w   = (const float*)d_in[5];
    const float* n1b   = (const float*)d_in[6];
    const float* n2w   = (const float*)d_in[7];
    const float* n2b   = (const float*)d_in[8];
    const float* w0    = (const float*)d_in[9];
    const float* as0   = (const float*)d_in[10];
    const float* ad0   = (const float*)d_in[11];
    const float* w1    = (const float*)d_in[12];
    const float* as1   = (const float*)d_in[13];
    const float* ad1   = (const float*)d_in[14];
    float* out = (float*)d_out;

    // workspace layout (ushort units)
    ushort* x0p  = (ushort*)d_ws;                 // 1,572,864
    ushort* wt0  = x0p + 1572864;                 // 196,608
    ushort* wt1  = wt0 + 196608;                  // 1,048,576
    ushort* hpT  = wt1 + 1048576;                 // 8,388,608
    ushort* x1bf = hpT + 8388608;                 // 8,388,608
    ushort* o1   = x1bf + 8388608;                // 8,388,608
    unsigned long long* mask = (unsigned long long*)(o1 + 8388608);  // 65,536 words
    float* sb = (float*)(mask + 65536);           // 65,536 f
    float* db = sb + 65536;                       // 65,536 f

    hipMemsetAsync(x0p, 0, (size_t)8192 * KP0_ * sizeof(ushort), stream);
    hipLaunchKernelGGL(k_copy_h,   dim3(2048), dim3(256), 0, stream, h, x0p);
    hipLaunchKernelGGL(k_emb_norm, dim3(1024), dim3(256), 0, stream, verts, table, n1w, n1b, x0p);
    hipLaunchKernelGGL(k_ue_norm,  dim3(48),   dim3(256), 0, stream, ue, n2w, n2b, x0p);
    hipLaunchKernelGGL((k_wt<FIN0_, KP0_>), dim3(8 * (KP0_ / 8)), dim3(128), 0, stream, w0, wt0);
    hipLaunchKernelGGL((k_wt<FIN1_, FIN1_>), dim3(8 * (FIN1_ / 8)), dim3(128), 0, stream, w1, wt1);
    hipLaunchKernelGGL(k_mask, dim3(16384), dim3(256), 0, stream, adj, mask);

    // layer 0
    hipLaunchKernelGGL((k_gemm<KP0_>), dim3(512), dim3(256), 0, stream, x0p, wt0, hpT);
    hipLaunchKernelGGL(k_sd, dim3(256), dim3(128), 0, stream, hpT, as0, ad0, sb, db);
    hipLaunchKernelGGL((k_attn<true>), dim3(2048), dim3(256), 0, stream, hpT, sb, db, mask, x1bf);

    // layer 1
    hipLaunchKernelGGL((k_gemm<FIN1_>), dim3(512), dim3(256), 0, stream, x1bf, wt1, hpT);
    hipLaunchKernelGGL(k_sd, dim3(256), dim3(128), 0, stream, hpT, as1, ad1, sb, db);
    hipLaunchKernelGGL((k_attn<false>), dim3(2048), dim3(256), 0, stream, hpT, sb, db, mask, o1);

    // mean over heads + log_softmax
    hipLaunchKernelGGL(k_out, dim3(8192), dim3(128), 0, stream, o1, out);
}

// Round 4
// 163.244 us; speedup vs baseline: 5.4387x; 1.2964x over previous
//
#include <hip/hip_runtime.h>
#include <hip/hip_bf16.h>
#include <cmath>

// Problem constants
#define B_  16
#define N_  512
#define H_  8
#define F0_ 64
#define DEMB_ 64
#define FIN0_ 131   // 64 + 64 + 3
#define KP0_ 192    // padded K for layer-0 GEMM
#define O_  128
#define FIN1_ 1024  // H_*O_

typedef __attribute__((ext_vector_type(4))) float f32x4;
typedef __attribute__((ext_vector_type(8))) short bf16x8;

__device__ inline ushort f2bf(float f) {
    union { float f; unsigned u; } x; x.f = f;
    unsigned r = x.u + 0x7fff + ((x.u >> 16) & 1);   // RNE
    return (ushort)(r >> 16);
}
__device__ inline float bf2f(ushort u) {
    union { unsigned u; float f; } x; x.u = ((unsigned)u) << 16;
    return x.f;
}
__device__ inline float tanh_fast(float x) {
    x = fminf(fmaxf(x, -15.f), 15.f);
    float e = __expf(2.f * x);
    return (e - 1.f) * __frcp_rn(e + 1.f);
}

// ---------------------------------------------------------------------------
// x0p build (bf16, [8192][192], zero-padded cols 131..191 via memset)
// ---------------------------------------------------------------------------
__global__ __launch_bounds__(256) void k_copy_h(const float* __restrict__ h,
                                                ushort* __restrict__ x0) {
    int i = blockIdx.x * 256 + threadIdx.x;   // over B*N*64
    int r = i >> 6, c = i & 63;
    x0[(size_t)r * KP0_ + c] = f2bf(h[i]);
}

__global__ __launch_bounds__(256) void k_emb_norm(const int* __restrict__ verts,
                                                  const float* __restrict__ table,
                                                  const float* __restrict__ w,
                                                  const float* __restrict__ bb,
                                                  ushort* __restrict__ x0) {
    int b = blockIdx.x >> 6, c = blockIdx.x & 63;
    int t = threadIdx.x;
    float vals[2], sum = 0.f, sq = 0.f;
#pragma unroll
    for (int i = 0; i < 2; ++i) {
        int n = t + i * 256;
        int vid = verts[b * N_ + n];
        float v = table[(size_t)vid * DEMB_ + c];
        vals[i] = v; sum += v; sq += v * v;
    }
    __shared__ float s0[256], s1[256];
    s0[t] = sum; s1[t] = sq; __syncthreads();
    for (int o = 128; o > 0; o >>= 1) {
        if (t < o) { s0[t] += s0[t + o]; s1[t] += s1[t + o]; }
        __syncthreads();
    }
    float mu = s0[0] * (1.f / N_);
    float var = s1[0] * (1.f / N_) - mu * mu;
    float inv = rsqrtf(var + 1e-5f);
    float ww = w[c], bv = bb[c];
#pragma unroll
    for (int i = 0; i < 2; ++i) {
        int n = t + i * 256;
        x0[((size_t)b * N_ + n) * KP0_ + 64 + c] = f2bf((vals[i] - mu) * inv * ww + bv);
    }
}

__global__ __launch_bounds__(256) void k_ue_norm(const float* __restrict__ ue,
                                                 const float* __restrict__ w,
                                                 const float* __restrict__ bb,
                                                 ushort* __restrict__ x0) {
    int b = blockIdx.x / 3, c = blockIdx.x % 3;
    int t = threadIdx.x;
    float vals[2], sum = 0.f, sq = 0.f;
#pragma unroll
    for (int i = 0; i < 2; ++i) {
        int n = t + i * 256;
        float v = ue[((size_t)b * N_ + n) * 3 + c];
        vals[i] = v; sum += v; sq += v * v;
    }
    __shared__ float s0[256], s1[256];
    s0[t] = sum; s1[t] = sq; __syncthreads();
    for (int o = 128; o > 0; o >>= 1) {
        if (t < o) { s0[t] += s0[t + o]; s1[t] += s1[t + o]; }
        __syncthreads();
    }
    float mu = s0[0] * (1.f / N_);
    float var = s1[0] * (1.f / N_) - mu * mu;
    float inv = rsqrtf(var + 1e-5f);
    float ww = w[c], bv = bb[c];
#pragma unroll
    for (int i = 0; i < 2; ++i) {
        int n = t + i * 256;
        x0[((size_t)b * N_ + n) * KP0_ + 128 + c] = f2bf((vals[i] - mu) * inv * ww + bv);
    }
}

// ---------------------------------------------------------------------------
// Weight transpose+convert: w [H][K][128] f32 -> wt [H][128][Kp] bf16 (pad 0)
// ---------------------------------------------------------------------------
template <int K, int Kp>
__global__ __launch_bounds__(128) void k_wt(const float* __restrict__ w,
                                            ushort* __restrict__ wt) {
    int hh = blockIdx.x / (Kp / 8);
    int kc = blockIdx.x % (Kp / 8);
    int o = threadIdx.x;
    bf16x8 v;
#pragma unroll
    for (int j = 0; j < 8; ++j) {
        int k = kc * 8 + j;
        float f = (k < K) ? w[((size_t)hh * K + k) * 128 + o] : 0.f;
        v[j] = (short)f2bf(f);
    }
    *(bf16x8*)(wt + ((size_t)(hh * 128 + o)) * Kp + kc * 8) = v;
}

// ---------------------------------------------------------------------------
// adj > 0 bitmask: word (b*512+n)*8 + c holds bits for m = c*64 .. c*64+63
// ---------------------------------------------------------------------------
__global__ __launch_bounds__(256) void k_mask(const float* __restrict__ adj,
                                              unsigned long long* __restrict__ mask) {
    int gid = blockIdx.x * 256 + threadIdx.x;
    float v = adj[gid];
    unsigned long long m = __ballot(v > 0.f);
    if ((threadIdx.x & 63) == 0) mask[gid >> 6] = m;
}

// ---------------------------------------------------------------------------
// MFMA GEMM + fused s/d: hpT[bh][o][n] = sum_k A[b*512+n][k] * Wt[h][o][k]
// s[bh][n] = sum_o tanh(hp)*a_src[h][o]; d likewise (fp32 acc, pre-bf16).
// Tile 128x128, BK=64, 4 waves (2x2 of 64x64), XOR-swizzled LDS,
// global_load_lds width-16 staging with pre-swizzled global source.
// ---------------------------------------------------------------------------
template <int K>
__global__ __launch_bounds__(256) void k_gemm(const ushort* __restrict__ A,
                                              const ushort* __restrict__ Wt,
                                              const float* __restrict__ asrc,
                                              const float* __restrict__ adst,
                                              ushort* __restrict__ hpT,
                                              float* __restrict__ sout,
                                              float* __restrict__ dout) {
    __shared__ ushort As[128 * 64];
    __shared__ ushort Bs[128 * 64];
    int bid = blockIdx.x;
    int hh = bid >> 6;           // head
    int mt = bid & 63;           // 128-row tile of M=8192
    int tid = threadIdx.x;
    int wid = tid >> 6, l = tid & 63;
    int wm = wid >> 1, wn = wid & 1;

    const ushort* Ab = A + (size_t)mt * 128 * K;
    const ushort* Wb = Wt + (size_t)hh * 128 * K;

    f32x4 acc[4][4];
#pragma unroll
    for (int m = 0; m < 4; ++m)
#pragma unroll
        for (int n = 0; n < 4; ++n) acc[m][n] = (f32x4){0.f, 0.f, 0.f, 0.f};

    int srow = tid >> 3;         // 0..31
    int segp = tid & 7;          // physical 16B slot

    for (int kt = 0; kt < K / 64; ++kt) {
        int k0 = kt * 64;
#pragma unroll
        for (int it = 0; it < 4; ++it) {
            int row = it * 32 + srow;
            int segl = segp ^ (row & 7);
            __builtin_amdgcn_global_load_lds(
                (const __attribute__((address_space(1))) void*)(Ab + (size_t)row * K + k0 + segl * 8),
                (__attribute__((address_space(3))) void*)(As + (it * 32 + wid * 8) * 64),
                16, 0, 0);
            __builtin_amdgcn_global_load_lds(
                (const __attribute__((address_space(1))) void*)(Wb + (size_t)row * K + k0 + segl * 8),
                (__attribute__((address_space(3))) void*)(Bs + (it * 32 + wid * 8) * 64),
                16, 0, 0);
        }
        __syncthreads();

        int lr = l & 15;
        int kg = l >> 4;
#pragma unroll
        for (int kk = 0; kk < 2; ++kk) {
            int segl = kk * 4 + kg;
            bf16x8 a[4], b[4];
#pragma unroll
            for (int m = 0; m < 4; ++m) {
                int row = wm * 64 + m * 16 + lr;
                int sp = segl ^ (row & 7);
                a[m] = *(const bf16x8*)(As + row * 64 + sp * 8);
            }
#pragma unroll
            for (int n = 0; n < 4; ++n) {
                int row = wn * 64 + n * 16 + lr;
                int sp = segl ^ (row & 7);
                b[n] = *(const bf16x8*)(Bs + row * 64 + sp * 8);
            }
#pragma unroll
            for (int m = 0; m < 4; ++m)
#pragma unroll
                for (int n = 0; n < 4; ++n)
                    acc[m][n] = __builtin_amdgcn_mfma_f32_16x16x32_bf16(a[m], b[n], acc[m][n], 0, 0, 0);
        }
        __syncthreads();
    }

    // epilogue 1: hpT write. D col=lane&15 (o), row=(lane>>4)*4+j (n).
    int bb = mt >> 2;
    int n_in_b = (mt & 3) * 128;
    int bh = bb * H_ + hh;
    ushort* Hp = hpT + ((size_t)bh * 128) * 512;
#pragma unroll
    for (int m = 0; m < 4; ++m)
#pragma unroll
        for (int n = 0; n < 4; ++n) {
            int rr = wm * 64 + m * 16 + (l >> 4) * 4;
            int cc = wn * 64 + n * 16 + (l & 15);
            ushort4 v;
            v.x = f2bf(acc[m][n][0]);
            v.y = f2bf(acc[m][n][1]);
            v.z = f2bf(acc[m][n][2]);
            v.w = f2bf(acc[m][n][3]);
            *(ushort4*)(Hp + (size_t)cc * 512 + n_in_b + rr) = v;
        }

    // epilogue 2: fused s/d row-reduce (tanh in fp32)
    float* sP = (float*)As;          // [2][128]
    float* dP = sP + 256;            // [2][128]
    float av[4], dv[4];
#pragma unroll
    for (int n = 0; n < 4; ++n) {
        int cc = wn * 64 + n * 16 + (l & 15);
        av[n] = asrc[hh * 128 + cc];
        dv[n] = adst[hh * 128 + cc];
    }
#pragma unroll
    for (int m = 0; m < 4; ++m)
#pragma unroll
        for (int j = 0; j < 4; ++j) {
            float sv = 0.f, dvv = 0.f;
#pragma unroll
            for (int n = 0; n < 4; ++n) {
                float th = tanh_fast(acc[m][n][j]);
                sv += th * av[n];
                dvv += th * dv[n];
            }
#pragma unroll
            for (int off = 1; off < 16; off <<= 1) {
                sv += __shfl_xor(sv, off);
                dvv += __shfl_xor(dvv, off);
            }
            if ((l & 15) == 0) {
                int rr = wm * 64 + m * 16 + (l >> 4) * 4 + j;
                sP[wn * 128 + rr] = sv;
                dP[wn * 128 + rr] = dvv;
            }
        }
    __syncthreads();
    if (tid < 128) {
        sout[(size_t)bh * 512 + n_in_b + tid] = sP[tid] + sP[128 + tid];
    } else {
        int r = tid - 128;
        dout[(size_t)bh * 512 + n_in_b + r] = dP[r] + dP[128 + r];
    }
}

// ---------------------------------------------------------------------------
// Fused masked softmax + MFMA PV.
// grid 2048: b = bid&15 (XCD pin), hh = (bid>>4)&7, tile = bid>>7 (32 rows).
// Single-pass softmax (no max subtraction; |logit| <= ~55 provable bound).
// P (unnormalized exp, bf16) in LDS, bijective swizzle:
//   phys_slot = s ^ (s>>3) ^ (row&7)  [s = 16B slot in row] — conflict-free
//   for both the (row,c)-oct writes and the (lr,lg4)-oct PV reads.
// ---------------------------------------------------------------------------
union ShU {
    ushort P[32 * 512];          // 32 KB
    float  T[4 * 32 * 36];       // per-wave transpose staging (18 KB)
};

template <bool L0>
__global__ __launch_bounds__(256, 4) void k_attn(const ushort* __restrict__ hpT,
                                                 const float* __restrict__ sbuf,
                                                 const float* __restrict__ dbuf,
                                                 const unsigned long long* __restrict__ mask,
                                                 ushort* __restrict__ out) {
    __shared__ ShU u;
    __shared__ float ds2[8 * 68];
    __shared__ float rs[32];

    int bid = blockIdx.x;
    int b = bid & 15, hh = (bid >> 4) & 7, tile = bid >> 7;
    int bh = b * 8 + hh;
    int n0 = tile * 32;
    int t = threadIdx.x;
    int wid = t >> 6, l = t & 63;

    int row = t >> 3, c = t & 7;
    // hoisted independent global loads
    unsigned long long mb = mask[((size_t)(b * 512 + n0 + row) << 3) + c];
    float sv = sbuf[(size_t)bh * 512 + n0 + row];

    // stage d (bank-swizzled: index m + 4*(m>>6))
    for (int m = t; m < 512; m += 256)
        ds2[m + ((m >> 6) << 2)] = dbuf[(size_t)bh * 512 + m];
    __syncthreads();

    // ---- single-pass softmax: unnormalized e -> P, rowsum -> rs ----
    const float* dsc = ds2 + c * 68;
    float sum = 0.f;
#pragma unroll
    for (int j = 0; j < 8; ++j) {
        f32x4 da = *(const f32x4*)(dsc + j * 8);
        f32x4 db2 = *(const f32x4*)(dsc + j * 8 + 4);
        bf16x8 pk;
#pragma unroll
        for (int q = 0; q < 8; ++q) {
            float dm = (q < 4) ? da[q] : db2[q - 4];
            float lg = sv + dm;
            lg = fmaxf(lg, 0.2f * lg);               // leaky_relu(0.2)
            float e = ((mb >> (j * 8 + q)) & 1) ? __expf(lg) : 0.f;
            sum += e;
            pk[q] = (short)f2bf(e);
        }
        int phys = c * 8 + (j ^ c ^ (row & 7));      // s ^ (s>>3) ^ (row&7)
        *(bf16x8*)((char*)u.P + row * 1024 + phys * 16) = pk;
    }
    sum += __shfl_xor(sum, 1);
    sum += __shfl_xor(sum, 2);
    sum += __shfl_xor(sum, 4);
    if (c == 0) rs[row] = sum;
    __syncthreads();

    // ---- PV: O^T[o 32/wave][n 32] = V^T x P^T via MFMA ----
    int lr = l & 15, lg4 = l >> 4;
    int ob = wid * 32;
    const ushort* Ab = hpT + ((size_t)(bh * 128 + ob + lr)) * 512 + lg4 * 8;

    f32x4 acc[2][2];
#pragma unroll
    for (int i = 0; i < 2; ++i)
#pragma unroll
        for (int j = 0; j < 2; ++j) acc[i][j] = (f32x4){0.f, 0.f, 0.f, 0.f};

#pragma unroll
    for (int ks = 0; ks < 16; ++ks) {
        int phys = (4 * ks + lg4) ^ (ks >> 1) ^ (lr & 7);
        bf16x8 a0 = *(const bf16x8*)(Ab + ks * 32);
        bf16x8 a1 = *(const bf16x8*)(Ab + 16 * 512 + ks * 32);
        bf16x8 b0 = *(const bf16x8*)((const char*)u.P + lr * 1024 + phys * 16);
        bf16x8 b1 = *(const bf16x8*)((const char*)u.P + (lr + 16) * 1024 + phys * 16);
        acc[0][0] = __builtin_amdgcn_mfma_f32_16x16x32_bf16(a0, b0, acc[0][0], 0, 0, 0);
        acc[1][0] = __builtin_amdgcn_mfma_f32_16x16x32_bf16(a1, b0, acc[1][0], 0, 0, 0);
        acc[0][1] = __builtin_amdgcn_mfma_f32_16x16x32_bf16(a0, b1, acc[0][1], 0, 0, 0);
        acc[1][1] = __builtin_amdgcn_mfma_f32_16x16x32_bf16(a1, b1, acc[1][1], 0, 0, 0);
    }
    __syncthreads();   // all waves done reading P before T overwrites it

    // normalize + per-wave transpose through LDS
    float rinv0 = __frcp_rn(rs[lr]);
    float rinv1 = __frcp_rn(rs[16 + lr]);
    float* Tw = u.T + wid * (32 * 36);
#pragma unroll
    for (int of = 0; of < 2; ++of)
#pragma unroll
        for (int nf = 0; nf < 2; ++nf) {
            float ri = nf ? rinv1 : rinv0;
#pragma unroll
            for (int j = 0; j < 4; ++j)
                Tw[(nf * 16 + lr) * 36 + of * 16 + lg4 * 4 + j] = acc[of][nf][j] * ri;
        }
    __syncthreads();

    int nr = l >> 1, oh = l & 1;
    ushort* op;
    if (L0)
        op = out + ((size_t)(b * 512 + n0 + nr)) * FIN1_ + hh * 128 + ob + oh * 16;
    else
        op = out + ((size_t)bh * 512 + n0 + nr) * 128 + ob + oh * 16;

    bf16x8 w0v, w1v;
#pragma unroll
    for (int j = 0; j < 4; ++j) {
        f32x4 v = *(const f32x4*)(Tw + nr * 36 + oh * 16 + j * 4);
#pragma unroll
        for (int q = 0; q < 4; ++q) {
            float f = v[q];
            if (L0) f = (f > 0.f) ? f : expm1f(f);
            if (j < 2) w0v[j * 4 + q] = (short)f2bf(f);
            else       w1v[(j - 2) * 4 + q] = (short)f2bf(f);
        }
    }
    *(bf16x8*)op = w0v;
    *(bf16x8*)(op + 8) = w1v;
}

// ---------------------------------------------------------------------------
// mean over heads (bf16 in) + log_softmax over channels(128)
// ---------------------------------------------------------------------------
__global__ __launch_bounds__(128) void k_out(const ushort* __restrict__ o1,
                                             float* __restrict__ out) {
    int row = blockIdx.x;       // b*512+n
    int b = row >> 9, n = row & 511;
    int t = threadIdx.x;
    float v = 0.f;
#pragma unroll
    for (int hh = 0; hh < H_; ++hh)
        v += bf2f(o1[((size_t)(b * H_ + hh) * N_ + n) * O_ + t]);
    v *= 0.125f;
    float m = v;
#pragma unroll
    for (int off = 32; off > 0; off >>= 1) m = fmaxf(m, __shfl_down(m, off));
    __shared__ float red[4];
    if ((t & 63) == 0) red[t >> 6] = m;
    __syncthreads();
    float rm = fmaxf(red[0], red[1]);
    float e = __expf(v - rm);
    float ss = e;
#pragma unroll
    for (int off = 32; off > 0; off >>= 1) ss += __shfl_down(ss, off);
    if ((t & 63) == 0) red[2 + (t >> 6)] = ss;
    __syncthreads();
    float rs2 = red[2] + red[3];
    out[(size_t)row * O_ + t] = v - rm - logf(rs2);
}

// ---------------------------------------------------------------------------
extern "C" void kernel_launch(void* const* d_in, const int* in_sizes, int n_in,
                              void* d_out, int out_size, void* d_ws, size_t ws_size,
                              hipStream_t stream) {
    const int*   verts = (const int*)d_in[0];
    const float* adj   = (const float*)d_in[1];
    const float* h     = (const float*)d_in[2];
    const float* ue    = (const float*)d_in[3];
    const float* table = (const float*)d_in[4];
    const float* n1w   = (const float*)d_in[5];
    const float* n1b   = (const float*)d_in[6];
    const float* n2w   = (const float*)d_in[7];
    const float* n2b   = (const float*)d_in[8];
    const float* w0    = (const float*)d_in[9];
    const float* as0   = (const float*)d_in[10];
    const float* ad0   = (const float*)d_in[11];
    const float* w1    = (const float*)d_in[12];
    const float* as1   = (const float*)d_in[13];
    const float* ad1   = (const float*)d_in[14];
    float* out = (float*)d_out;

    // workspace layout (ushort units)
    ushort* x0p  = (ushort*)d_ws;                 // 1,572,864
    ushort* wt0  = x0p + 1572864;                 // 196,608
    ushort* wt1  = wt0 + 196608;                  // 1,048,576
    ushort* hpT  = wt1 + 1048576;                 // 8,388,608
    ushort* x1bf = hpT + 8388608;                 // 8,388,608
    ushort* o1   = x1bf + 8388608;                // 8,388,608
    unsigned long long* mask = (unsigned long long*)(o1 + 8388608);  // 65,536 words
    float* sb = (float*)(mask + 65536);           // 65,536 f
    float* db = sb + 65536;                       // 65,536 f

    hipMemsetAsync(x0p, 0, (size_t)8192 * KP0_ * sizeof(ushort), stream);
    hipLaunchKernelGGL(k_copy_h,   dim3(2048), dim3(256), 0, stream, h, x0p);
    hipLaunchKernelGGL(k_emb_norm, dim3(1024), dim3(256), 0, stream, verts, table, n1w, n1b, x0p);
    hipLaunchKernelGGL(k_ue_norm,  dim3(48),   dim3(256), 0, stream, ue, n2w, n2b, x0p);
    hipLaunchKernelGGL((k_wt<FIN0_, KP0_>), dim3(8 * (KP0_ / 8)), dim3(128), 0, stream, w0, wt0);
    hipLaunchKernelGGL((k_wt<FIN1_, FIN1_>), dim3(8 * (FIN1_ / 8)), dim3(128), 0, stream, w1, wt1);
    hipLaunchKernelGGL(k_mask, dim3(16384), dim3(256), 0, stream, adj, mask);

    // layer 0 (s/d fused into GEMM epilogue)
    hipLaunchKernelGGL((k_gemm<KP0_>), dim3(512), dim3(256), 0, stream,
                       x0p, wt0, as0, ad0, hpT, sb, db);
    hipLaunchKernelGGL((k_attn<true>), dim3(2048), dim3(256), 0, stream, hpT, sb, db, mask, x1bf);

    // layer 1
    hipLaunchKernelGGL((k_gemm<FIN1_>), dim3(512), dim3(256), 0, stream,
                       x1bf, wt1, as1, ad1, hpT, sb, db);
    hipLaunchKernelGGL((k_attn<false>), dim3(2048), dim3(256), 0, stream, hpT, sb, db, mask, o1);

    // mean over heads + log_softmax
    hipLaunchKernelGGL(k_out, dim3(8192), dim3(128), 0, stream, o1, out);
}